// Round 20
// baseline (92.932 us; speedup 1.0000x reference)
//
#include <hip/hip_runtime.h>
#include <math.h>

#define PI_F 3.14159265358979323846f

typedef _Float16 half2_t __attribute__((ext_vector_type(2)));
typedef _Float16 f16x8 __attribute__((ext_vector_type(8)));
typedef float f32x4v __attribute__((ext_vector_type(4)));

__device__ __forceinline__ unsigned packh2(float lo, float hi) {
  unsigned short l = __builtin_bit_cast(unsigned short, (_Float16)lo);
  unsigned short h = __builtin_bit_cast(unsigned short, (_Float16)hi);
  return (unsigned)l | ((unsigned)h << 16);
}

__device__ __forceinline__ unsigned pk16(_Float16 a, _Float16 b) {
  unsigned short ua = __builtin_bit_cast(unsigned short, a);
  unsigned short ub = __builtin_bit_cast(unsigned short, b);
  return (unsigned)ua | ((unsigned)ub << 16);
}

struct c2 { float x, y; };
__device__ __forceinline__ c2 cmul(c2 a, c2 b){ return c2{a.x*b.x - a.y*b.y, a.x*b.y + a.y*b.x}; }
__device__ __forceinline__ c2 cadd(c2 a, c2 b){ return c2{a.x+b.x, a.y+b.y}; }

__device__ __forceinline__ void rot2(c2 &a, c2 &b, c2 g00, c2 g01, c2 g10, c2 g11) {
  c2 na = cadd(cmul(g00,a), cmul(g01,b));
  c2 nb = cadd(cmul(g10,a), cmul(g11,b));
  a = na; b = nb;
}

__device__ __forceinline__ void mk_u3(float th, float ph, float la,
                                      c2 &g00, c2 &g01, c2 &g10, c2 &g11) {
  float ch = cosf(0.5f*th), sh = sinf(0.5f*th);
  float cl = cosf(la), sl = sinf(la);
  float cp = cosf(ph), sp = sinf(ph);
  float cpl = cp*cl - sp*sl, spl = sp*cl + cp*sl;
  g00 = c2{ch, 0.f};
  g01 = c2{-cl*sh, -sl*sh};
  g10 = c2{cp*sh, sp*sh};
  g11 = c2{cpl*ch, spl*ch};
}

template<int MA, int MB>
__device__ __forceinline__ void apply2q(c2 psi[16], const c2 M[16]) {
#pragma unroll
  for (int r = 0; r < 16; ++r) {
    if (r & (MA | MB)) continue;
    c2 a = psi[r], b = psi[r|MB], c = psi[r|MA], d = psi[r|MA|MB];
    psi[r]        = cadd(cadd(cmul(M[0],a),  cmul(M[1],b)),  cadd(cmul(M[2],c),  cmul(M[3],d)));
    psi[r|MB]     = cadd(cadd(cmul(M[4],a),  cmul(M[5],b)),  cadd(cmul(M[6],c),  cmul(M[7],d)));
    psi[r|MA]     = cadd(cadd(cmul(M[8],a),  cmul(M[9],b)),  cadd(cmul(M[10],c), cmul(M[11],d)));
    psi[r|MA|MB]  = cadd(cadd(cmul(M[12],a), cmul(M[13],b)), cadd(cmul(M[14],c), cmul(M[15],d)));
  }
}

// ------- Ksetup: blocks 0..166 = weight transposes/packs; block 167 = qmat. -------
__global__ __launch_bounds__(256) void k_setup(const float* __restrict__ w1a, const float* __restrict__ w1b,
                                               const float* __restrict__ w2a, const float* __restrict__ w2b,
                                               const float* __restrict__ c2w,
                                               const float* __restrict__ c1w, const float* __restrict__ c1b,
                                               const float* __restrict__ qw_u3,
                                               const float* __restrict__ qw_ang,
                                               float* __restrict__ wt, float* __restrict__ A) {
  __shared__ c2 SU[2][16];
  __shared__ float Ur[16*17], Ui[16*17];
  int t = threadIdx.x;
  if (blockIdx.x == 167) {
    if (t < 8) {
      int L = t >> 2, col = t & 3;
      c2 s[4];
#pragma unroll
      for (int i = 0; i < 4; ++i) s[i] = c2{(i==col)?1.f:0.f, 0.f};
      const float* u = qw_u3 + 12*L;
      const float* g = qw_ang + 3*L;
      c2 g00,g01,g10,g11;
      mk_u3(u[0],u[1],u[2], g00,g01,g10,g11);
      rot2(s[0],s[2], g00,g01,g10,g11); rot2(s[1],s[3], g00,g01,g10,g11);
      mk_u3(u[3],u[4],u[5], g00,g01,g10,g11);
      rot2(s[0],s[1], g00,g01,g10,g11); rot2(s[2],s[3], g00,g01,g10,g11);
      { c2 tmp = s[2]; s[2] = s[3]; s[3] = tmp; }
      { float c = cosf(0.5f*g[0]), sn = sinf(0.5f*g[0]);
        c2 r00{c,0.f}, r01{-sn,0.f}, r10{sn,0.f}, r11{c,0.f};
        rot2(s[0],s[2], r00,r01,r10,r11); rot2(s[1],s[3], r00,r01,r10,r11); }
      { float c = cosf(0.5f*g[1]), sn = sinf(0.5f*g[1]);
        c2 e0{c,-sn}, e1{c,sn};
        s[0]=cmul(s[0],e0); s[1]=cmul(s[1],e1); s[2]=cmul(s[2],e0); s[3]=cmul(s[3],e1); }
      { c2 tmp = s[1]; s[1] = s[3]; s[3] = tmp; }
      { float c = cosf(0.5f*g[2]), sn = sinf(0.5f*g[2]);
        c2 r00{c,0.f}, r01{-sn,0.f}, r10{sn,0.f}, r11{c,0.f};
        rot2(s[0],s[2], r00,r01,r10,r11); rot2(s[1],s[3], r00,r01,r10,r11); }
      { c2 tmp = s[2]; s[2] = s[3]; s[3] = tmp; }
      mk_u3(u[6],u[7],u[8], g00,g01,g10,g11);
      rot2(s[0],s[2], g00,g01,g10,g11); rot2(s[1],s[3], g00,g01,g10,g11);
      mk_u3(u[9],u[10],u[11], g00,g01,g10,g11);
      rot2(s[0],s[1], g00,g01,g10,g11); rot2(s[2],s[3], g00,g01,g10,g11);
#pragma unroll
      for (int k = 0; k < 4; ++k) SU[L][k*4 + col] = s[k];
    }
    __syncthreads();
    if (t < 16) {
      c2 psi[16];
#pragma unroll
      for (int i = 0; i < 16; ++i) psi[i] = c2{(i==t)?1.f:0.f, 0.f};
#pragma unroll
      for (int l = 0; l < 2; ++l) {
        c2 M[16];
#pragma unroll
        for (int k = 0; k < 16; ++k) M[k] = SU[l][k];
        apply2q<8,4>(psi, M);
        apply2q<4,2>(psi, M);
        apply2q<2,1>(psi, M);
        apply2q<1,8>(psi, M);
      }
#pragma unroll
      for (int k = 0; k < 16; ++k) { Ur[k*17+t] = psi[k].x; Ui[k*17+t] = psi[k].y; }
    }
    __syncthreads();
    {
      int i = t >> 4, j = t & 15;
      float a0=0.f,a1=0.f,a2=0.f,a3=0.f;
#pragma unroll
      for (int k = 0; k < 16; ++k) {
        float pr = Ur[k*17+i]*Ur[k*17+j] + Ui[k*17+i]*Ui[k*17+j];
        a0 += ((k>>3)&1) ? -pr : pr;
        a1 += ((k>>2)&1) ? -pr : pr;
        a2 += ((k>>1)&1) ? -pr : pr;
        a3 += ( k     &1) ? -pr : pr;
      }
      A[0*256 + t] = a0; A[1*256 + t] = a1; A[2*256 + t] = a2; A[3*256 + t] = a3;
    }
    return;
  }
  int id = blockIdx.x*256 + t;
  if (id < 16384) { int j = id >> 6, o = id & 63;  wt[id] = w1a[o*256 + j]; return; }
  int id1 = id - 16384;
  if (id1 < 8192)  { int j = id1 >> 7, o = id1 & 127; wt[16384 + id1] = w1b[o*64 + j]; return; }
  int id2 = id1 - 8192;
  if (id2 < 8192)  { int j = id2 >> 6, o = id2 & 63;  wt[24576 + id2] = w2a[o*128 + j]; return; }
  int id3 = id2 - 8192;
  if (id3 < 640)   { int j = id3 / 10, o = id3 % 10;  wt[32768 + id3] = w2b[o*64 + j]; return; }
  int id4 = id3 - 640;
  if (id4 < 4608) {
    int s = id4 >> 8, rem = id4 & 255, l = rem >> 2, r = rem & 3;
    int tap = s >> 1, h = s & 1;
    int oc = l & 15, j = l >> 4;
    int icl = 16*h + 4*j + r;
    float lo = c2w[oc*576 + icl*9 + tap];
    float hi = c2w[oc*576 + (icl+32)*9 + tap];
    ((unsigned*)wt)[33408 + id4] = packh2(lo, hi);
    return;
  }
  int id5 = id4 - 4608;
  if (id5 < 1024) {
    int nt = id5 >> 8, rem = id5 & 255, l = rem >> 2, r = rem & 3;
    int oc = nt*16 + (l & 15), j = l >> 4;
    int k0 = 8*j + 2*r;
    float lo = (k0     < 27) ? c1w[oc*27 + k0]     : 0.f;
    float hi = (k0 + 1 < 27) ? c1w[oc*27 + k0 + 1] : 0.f;
    ((unsigned*)wt)[38016 + id5] = packh2(lo, hi);
  }
}

// ---- K12 v3: FUSED conv1+pool -> conv2+pool. xs stored f16 (RNE at staging ==
// RNE at pack => bit-identical downstream). LDS 53.6 KB -> 3 blocks/CU (24
// waves, +50% latency hiding vs v2). A-frag build: 8 u16 LDS reads + shift/or.
__global__ __launch_bounds__(512, 6) void k_conv12(
    const float* __restrict__ x,
    const uint4* __restrict__ B1g, const float* __restrict__ b1,
    const uint4* __restrict__ B2g, const float* __restrict__ b2,
    float* __restrict__ h2) {
  __shared__ _Float16 xs[3468];        // [3][34][34] f16, strides 1156/34
  __shared__ unsigned hsp[11664];      // [18][18][36] u32
  int b = blockIdx.x, t = threadIdx.x;
  int l = t & 63, w = t >> 6;          // 8 waves
  int m = l & 15, j = l >> 4;
  uint4 Bf1[4];
#pragma unroll
  for (int nt = 0; nt < 4; ++nt) Bf1[nt] = B1g[nt*64 + l];
  float bz1[4];
#pragma unroll
  for (int nt = 0; nt < 4; ++nt) bz1[nt] = b1[nt*16 + m];
  int offs[8]; bool valid[8];
#pragma unroll
  for (int q = 0; q < 8; ++q) {
    int kk = 8*j + q;
    valid[q] = (kk < 27);
    int kc = valid[q] ? kk : 0;
    int c = kc / 9, rem = kc - 9*c, wr = rem / 3, cc = rem - 3*wr;
    offs[q] = c*1156 + wr*34 + cc;
  }
  {
    unsigned* xz = (unsigned*)xs;      // 1734 u32
    for (int i = t; i < 1734; i += 512) xz[i] = 0u;
    uint4 z = make_uint4(0u,0u,0u,0u);
    uint4* hz = (uint4*)hsp;
    for (int i = t; i < 2916; i += 512) hz[i] = z;
  }
  __syncthreads();
  for (int i = t; i < 3072; i += 512) {
    int c = i >> 10, rem = i & 1023, gy = rem >> 5, gx = rem & 31;
    xs[c*1156 + (gy+1)*34 + gx + 1] = (_Float16)x[(size_t)b*3072 + i];
  }
  __syncthreads();
  // ---- conv1 (MFMA) ----
#pragma unroll
  for (int h = 0; h < 2; ++h) {
    f32x4v acc[2][2][4];
#pragma unroll
    for (int rr = 0; rr < 2; ++rr)
#pragma unroll
      for (int xh = 0; xh < 2; ++xh)
#pragma unroll
        for (int nt = 0; nt < 4; ++nt)
          acc[rr][xh][nt] = f32x4v{bz1[nt], bz1[nt], bz1[nt], bz1[nt]};
#pragma unroll
    for (int rr = 0; rr < 2; ++rr)
#pragma unroll
      for (int xh = 0; xh < 2; ++xh) {
        int base = (16*h + 2*w + rr)*34 + 16*xh + m;
        _Float16 v[8];
#pragma unroll
        for (int q = 0; q < 8; ++q) v[q] = valid[q] ? xs[offs[q] + base] : (_Float16)0.f;
        uint4 Au = make_uint4(pk16(v[0], v[1]), pk16(v[2], v[3]),
                              pk16(v[4], v[5]), pk16(v[6], v[7]));
        f16x8 Av = __builtin_bit_cast(f16x8, Au);
#pragma unroll
        for (int nt = 0; nt < 4; ++nt)
          acc[rr][xh][nt] = __builtin_amdgcn_mfma_f32_16x16x32_f16(
              Av, __builtin_bit_cast(f16x8, Bf1[nt]), acc[rr][xh][nt], 0, 0, 0);
      }
    {
      int pyg = 8*h + w;
#pragma unroll
      for (int ntp = 0; ntp < 2; ++ntp)
#pragma unroll
        for (int xh = 0; xh < 2; ++xh)
#pragma unroll
          for (int pv = 0; pv < 2; ++pv) {
            f32x4v aL0 = acc[0][xh][ntp],   aL1 = acc[1][xh][ntp];
            f32x4v aH0 = acc[0][xh][ntp+2], aH1 = acc[1][xh][ntp+2];
            float mlo = fmaxf(fmaxf(aL0[2*pv], aL0[2*pv+1]), fmaxf(aL1[2*pv], aL1[2*pv+1]));
            float mhi = fmaxf(fmaxf(aH0[2*pv], aH0[2*pv+1]), fmaxf(aH1[2*pv], aH1[2*pv+1]));
            int px = 8*xh + 2*j + pv;
            hsp[((pyg+1)*18 + px + 1)*36 + ntp*16 + m] =
                packh2(fmaxf(mlo, 0.f), fmaxf(mhi, 0.f));
          }
    }
  }
  __syncthreads();
  // ---- conv2 (MFMA) ----
  uint4 Bf2[18];
#pragma unroll
  for (int s = 0; s < 18; ++s) Bf2[s] = B2g[s*64 + l];
  float bz2 = b2[m];
  f32x4v a2[2];
  a2[0] = f32x4v{bz2, bz2, bz2, bz2};
  a2[1] = f32x4v{bz2, bz2, bz2, bz2};
#pragma unroll
  for (int s = 0; s < 18; ++s) {
    const int tap = s >> 1, hh = s & 1;
    const int dy = tap / 3, dx = tap % 3;
    f16x8 Bv = __builtin_bit_cast(f16x8, Bf2[s]);
#pragma unroll
    for (int tt = 0; tt < 2; ++tt) {
      int y = 2*w + tt;
      f16x8 Av = __builtin_bit_cast(f16x8,
          *(const uint4*)(hsp + ((y+dy)*18 + m + dx)*36 + 16*hh + 4*j));
      a2[tt] = __builtin_amdgcn_mfma_f32_16x16x32_f16(Av, Bv, a2[tt], 0, 0, 0);
    }
  }
  float* outb = h2 + (size_t)b*1024 + m*64;
#pragma unroll
  for (int vp = 0; vp < 2; ++vp) {
    float mm = fmaxf(fmaxf(a2[0][2*vp], a2[0][2*vp+1]),
                     fmaxf(a2[1][2*vp], a2[1][2*vp+1]));
    outb[w*8 + 2*j + vp] = fmaxf(mm, 0.f);
  }
}

// ---- Ktail v2 (r18, clean): one image per block, 4 blocks/CU, phase-parallel. ----
__global__ __launch_bounds__(256) void k_tail(const float* __restrict__ h2, const float* __restrict__ w,
                                              const float* __restrict__ bias, const float* __restrict__ Ag,
                                              const float* __restrict__ wt,
                                              const float* __restrict__ b1a, const float* __restrict__ b1b,
                                              const float* __restrict__ b2a, const float* __restrict__ b2b,
                                              float* __restrict__ out) {
  __shared__ float h3s[1600];
  __shared__ float As[1024];
  __shared__ float c3s[4][64];
  __shared__ float qs[256];
  __shared__ float red[256];
  __shared__ float h1s[64];
  __shared__ float hbv[128];
  __shared__ float h3v[64];
  int b = blockIdx.x, t = threadIdx.x;
#pragma unroll
  for (int k = 0; k < 4; ++k) As[k*256 + t] = Ag[k*256 + t];
  for (int i = t; i < 1600; i += 256) h3s[i] = 0.f;
  __syncthreads();
  {
    const float4* src = (const float4*)(h2 + (size_t)b*1024);
    float4 v = src[t];
    int e = 4*t;
    int ic = e >> 6, iy = (e >> 3) & 7, ix = e & 7;
    float* d = &h3s[ic*100 + (iy+1)*10 + ix + 1];
    d[0]=v.x; d[1]=v.y; d[2]=v.z; d[3]=v.w;
  }
  __syncthreads();
  {
    int oc = t >> 6, pos = t & 63;
    int y = pos >> 3, xo = pos & 7;
    float acc = bias[oc];
    const float* wp = w + oc*144;
    for (int ic = 0; ic < 16; ++ic) {
#pragma unroll
      for (int ky = 0; ky < 3; ++ky)
#pragma unroll
        for (int kx = 0; kx < 3; ++kx)
          acc = fmaf(wp[ic*9 + ky*3 + kx], h3s[ic*100 + (y+ky)*10 + (xo+kx)], acc);
    }
    c3s[oc][pos] = acc;
  }
  __syncthreads();
  {
    int p = t & 63, w4 = t >> 6;
    float v0[2], v1[2], v2[2], v3[2];
#pragma unroll
    for (int o = 0; o < 4; ++o) {
      float v = c3s[o][p];
      float lv = v > 0.f ? v : 0.01f*v;
      float sg = 1.f/(1.f + expf(-lv));
      float sv, cv;
      __sincosf(sg * (0.5f*PI_F), &sv, &cv);
      float* dst = (o==0)?v0:(o==1)?v1:(o==2)?v2:v3;
      dst[0] = cv; dst[1] = sv;
    }
    float pv[16];
#pragma unroll
    for (int i = 0; i < 16; ++i)
      pv[i] = v0[(i>>3)&1] * v1[(i>>2)&1] * v2[(i>>1)&1] * v3[i&1];
    const float4* Aw = (const float4*)(As + w4*256);
    float a = 0.f;
#pragma unroll
    for (int i = 0; i < 16; ++i) {
      float d = 0.f;
#pragma unroll
      for (int j4 = 0; j4 < 4; ++j4) {
        float4 av = Aw[i*4 + j4];
        d = fmaf(av.x, pv[j4*4+0], d);
        d = fmaf(av.y, pv[j4*4+1], d);
        d = fmaf(av.z, pv[j4*4+2], d);
        d = fmaf(av.w, pv[j4*4+3], d);
      }
      a = fmaf(pv[i], d, a);
    }
    qs[p*4 + w4] = a;
  }
  __syncthreads();
  const float* WT1a = wt;
  const float* WT1b = wt + 16384;
  const float* WT2a = wt + 24576;
  const float* WT2b = wt + 32768;
  {
    int o = t & 63, seg = t >> 6;
    float acc = 0.f;
    const float* wp = WT1a + seg*64*64 + o;
    const float* qp = qs + seg*64;
    for (int jj = 0; jj < 64; ++jj) acc = fmaf(wp[jj*64], qp[jj], acc);
    red[seg*64 + o] = acc;
  }
  __syncthreads();
  if (t < 64) {
    float s = red[t] + red[64+t] + red[128+t] + red[192+t] + b1a[t];
    h1s[t] = fmaxf(s, 0.f);
  }
  __syncthreads();
  if (t < 128) {
    float acc = b1b[t];
    for (int jj = 0; jj < 64; ++jj) acc = fmaf(WT1b[jj*128 + t], h1s[jj], acc);
    hbv[t] = acc;
  }
  __syncthreads();
  {
    int o = t & 63, seg = t >> 6;
    float acc = 0.f;
    const float* wp = WT2a + seg*32*64 + o;
    const float* hp = hbv + seg*32;
    for (int jj = 0; jj < 32; ++jj) acc = fmaf(wp[jj*64], hp[jj], acc);
    red[seg*64 + o] = acc;
  }
  __syncthreads();
  if (t < 64) {
    float s = red[t] + red[64+t] + red[128+t] + red[192+t] + b2a[t];
    h3v[t] = fmaxf(s, 0.f);
  }
  __syncthreads();
  if (t < 10) {
    float o = b2b[t];
    for (int jj = 0; jj < 64; ++jj) o = fmaf(WT2b[jj*10 + t], h3v[jj], o);
    out[(size_t)b*10 + t] = o;
  }
}

extern "C" void kernel_launch(void* const* d_in, const int* in_sizes, int n_in,
                              void* d_out, int out_size, void* d_ws, size_t ws_size,
                              hipStream_t stream) {
  const float* x       = (const float*)d_in[0];
  const float* conv1_w = (const float*)d_in[1];
  const float* conv1_b = (const float*)d_in[2];
  const float* conv2_w = (const float*)d_in[3];
  const float* conv2_b = (const float*)d_in[4];
  const float* conv3_w = (const float*)d_in[5];
  const float* conv3_b = (const float*)d_in[6];
  const float* qw_u3   = (const float*)d_in[7];
  const float* qw_ang  = (const float*)d_in[8];
  const float* fc1a_w  = (const float*)d_in[9];
  const float* fc1a_b  = (const float*)d_in[10];
  const float* fc1b_w  = (const float*)d_in[11];
  const float* fc1b_b  = (const float*)d_in[12];
  const float* fc2a_w  = (const float*)d_in[13];
  const float* fc2a_b  = (const float*)d_in[14];
  const float* fc2b_w  = (const float*)d_in[15];
  const float* fc2b_b  = (const float*)d_in[16];
  float* out = (float*)d_out;

  float* ws  = (float*)d_ws;
  float* A   = ws;                      // 1024 floats
  float* WT  = ws + 1024;               // fc transposes (33408) + conv2 B (4608 u32) + conv1 B (1024 u32)
  const uint4* BG  = (const uint4*)((const unsigned*)WT + 33408);
  const uint4* B1G = (const uint4*)((const unsigned*)WT + 38016);
  float* h2  = ws + 17083008;           // 1048576 floats (1024x16x8x8)

  k_setup <<<168,  256, 0, stream>>>(fc1a_w, fc1b_w, fc2a_w, fc2b_w, conv2_w, conv1_w, conv1_b,
                                     qw_u3, qw_ang, WT, A);
  k_conv12<<<1024, 512, 0, stream>>>(x, B1G, conv1_b, BG, conv2_b, h2);
  k_tail  <<<1024, 256, 0, stream>>>(h2, conv3_w, conv3_b, A, WT,
                                     fc1a_b, fc1b_b, fc2a_b, fc2b_b, out);
}

// Round 21
// 46.410 us; speedup vs baseline: 2.0024x; 2.0024x over previous
//
#include <hip/hip_runtime.h>
#include <math.h>

#define PI_F 3.14159265358979323846f

typedef _Float16 half2_t __attribute__((ext_vector_type(2)));
typedef _Float16 f16x8 __attribute__((ext_vector_type(8)));
typedef float f32x4v __attribute__((ext_vector_type(4)));

__device__ __forceinline__ unsigned packh2(float lo, float hi) {
  unsigned short l = __builtin_bit_cast(unsigned short, (_Float16)lo);
  unsigned short h = __builtin_bit_cast(unsigned short, (_Float16)hi);
  return (unsigned)l | ((unsigned)h << 16);
}

struct c2 { float x, y; };
__device__ __forceinline__ c2 cmul(c2 a, c2 b){ return c2{a.x*b.x - a.y*b.y, a.x*b.y + a.y*b.x}; }
__device__ __forceinline__ c2 cadd(c2 a, c2 b){ return c2{a.x+b.x, a.y+b.y}; }

__device__ __forceinline__ void rot2(c2 &a, c2 &b, c2 g00, c2 g01, c2 g10, c2 g11) {
  c2 na = cadd(cmul(g00,a), cmul(g01,b));
  c2 nb = cadd(cmul(g10,a), cmul(g11,b));
  a = na; b = nb;
}

__device__ __forceinline__ void mk_u3(float th, float ph, float la,
                                      c2 &g00, c2 &g01, c2 &g10, c2 &g11) {
  float ch = cosf(0.5f*th), sh = sinf(0.5f*th);
  float cl = cosf(la), sl = sinf(la);
  float cp = cosf(ph), sp = sinf(ph);
  float cpl = cp*cl - sp*sl, spl = sp*cl + cp*sl;
  g00 = c2{ch, 0.f};
  g01 = c2{-cl*sh, -sl*sh};
  g10 = c2{cp*sh, sp*sh};
  g11 = c2{cpl*ch, spl*ch};
}

template<int MA, int MB>
__device__ __forceinline__ void apply2q(c2 psi[16], const c2 M[16]) {
#pragma unroll
  for (int r = 0; r < 16; ++r) {
    if (r & (MA | MB)) continue;
    c2 a = psi[r], b = psi[r|MB], c = psi[r|MA], d = psi[r|MA|MB];
    psi[r]        = cadd(cadd(cmul(M[0],a),  cmul(M[1],b)),  cadd(cmul(M[2],c),  cmul(M[3],d)));
    psi[r|MB]     = cadd(cadd(cmul(M[4],a),  cmul(M[5],b)),  cadd(cmul(M[6],c),  cmul(M[7],d)));
    psi[r|MA]     = cadd(cadd(cmul(M[8],a),  cmul(M[9],b)),  cadd(cmul(M[10],c), cmul(M[11],d)));
    psi[r|MA|MB]  = cadd(cadd(cmul(M[12],a), cmul(M[13],b)), cadd(cmul(M[14],c), cmul(M[15],d)));
  }
}

// ------- Ksetup: blocks 0..166 = weight transposes/packs; block 167 = qmat. -------
__global__ __launch_bounds__(256) void k_setup(const float* __restrict__ w1a, const float* __restrict__ w1b,
                                               const float* __restrict__ w2a, const float* __restrict__ w2b,
                                               const float* __restrict__ c2w,
                                               const float* __restrict__ c1w, const float* __restrict__ c1b,
                                               const float* __restrict__ qw_u3,
                                               const float* __restrict__ qw_ang,
                                               float* __restrict__ wt, float* __restrict__ A) {
  __shared__ c2 SU[2][16];
  __shared__ float Ur[16*17], Ui[16*17];
  int t = threadIdx.x;
  if (blockIdx.x == 167) {
    if (t < 8) {
      int L = t >> 2, col = t & 3;
      c2 s[4];
#pragma unroll
      for (int i = 0; i < 4; ++i) s[i] = c2{(i==col)?1.f:0.f, 0.f};
      const float* u = qw_u3 + 12*L;
      const float* g = qw_ang + 3*L;
      c2 g00,g01,g10,g11;
      mk_u3(u[0],u[1],u[2], g00,g01,g10,g11);
      rot2(s[0],s[2], g00,g01,g10,g11); rot2(s[1],s[3], g00,g01,g10,g11);
      mk_u3(u[3],u[4],u[5], g00,g01,g10,g11);
      rot2(s[0],s[1], g00,g01,g10,g11); rot2(s[2],s[3], g00,g01,g10,g11);
      { c2 tmp = s[2]; s[2] = s[3]; s[3] = tmp; }
      { float c = cosf(0.5f*g[0]), sn = sinf(0.5f*g[0]);
        c2 r00{c,0.f}, r01{-sn,0.f}, r10{sn,0.f}, r11{c,0.f};
        rot2(s[0],s[2], r00,r01,r10,r11); rot2(s[1],s[3], r00,r01,r10,r11); }
      { float c = cosf(0.5f*g[1]), sn = sinf(0.5f*g[1]);
        c2 e0{c,-sn}, e1{c,sn};
        s[0]=cmul(s[0],e0); s[1]=cmul(s[1],e1); s[2]=cmul(s[2],e0); s[3]=cmul(s[3],e1); }
      { c2 tmp = s[1]; s[1] = s[3]; s[3] = tmp; }
      { float c = cosf(0.5f*g[2]), sn = sinf(0.5f*g[2]);
        c2 r00{c,0.f}, r01{-sn,0.f}, r10{sn,0.f}, r11{c,0.f};
        rot2(s[0],s[2], r00,r01,r10,r11); rot2(s[1],s[3], r00,r01,r10,r11); }
      { c2 tmp = s[2]; s[2] = s[3]; s[3] = tmp; }
      mk_u3(u[6],u[7],u[8], g00,g01,g10,g11);
      rot2(s[0],s[2], g00,g01,g10,g11); rot2(s[1],s[3], g00,g01,g10,g11);
      mk_u3(u[9],u[10],u[11], g00,g01,g10,g11);
      rot2(s[0],s[1], g00,g01,g10,g11); rot2(s[2],s[3], g00,g01,g10,g11);
#pragma unroll
      for (int k = 0; k < 4; ++k) SU[L][k*4 + col] = s[k];
    }
    __syncthreads();
    if (t < 16) {
      c2 psi[16];
#pragma unroll
      for (int i = 0; i < 16; ++i) psi[i] = c2{(i==t)?1.f:0.f, 0.f};
#pragma unroll
      for (int l = 0; l < 2; ++l) {
        c2 M[16];
#pragma unroll
        for (int k = 0; k < 16; ++k) M[k] = SU[l][k];
        apply2q<8,4>(psi, M);
        apply2q<4,2>(psi, M);
        apply2q<2,1>(psi, M);
        apply2q<1,8>(psi, M);
      }
#pragma unroll
      for (int k = 0; k < 16; ++k) { Ur[k*17+t] = psi[k].x; Ui[k*17+t] = psi[k].y; }
    }
    __syncthreads();
    {
      int i = t >> 4, j = t & 15;
      float a0=0.f,a1=0.f,a2=0.f,a3=0.f;
#pragma unroll
      for (int k = 0; k < 16; ++k) {
        float pr = Ur[k*17+i]*Ur[k*17+j] + Ui[k*17+i]*Ui[k*17+j];
        a0 += ((k>>3)&1) ? -pr : pr;
        a1 += ((k>>2)&1) ? -pr : pr;
        a2 += ((k>>1)&1) ? -pr : pr;
        a3 += ( k     &1) ? -pr : pr;
      }
      A[0*256 + t] = a0; A[1*256 + t] = a1; A[2*256 + t] = a2; A[3*256 + t] = a3;
    }
    return;
  }
  int id = blockIdx.x*256 + t;
  if (id < 16384) { int j = id >> 6, o = id & 63;  wt[id] = w1a[o*256 + j]; return; }
  int id1 = id - 16384;
  if (id1 < 8192)  { int j = id1 >> 7, o = id1 & 127; wt[16384 + id1] = w1b[o*64 + j]; return; }
  int id2 = id1 - 8192;
  if (id2 < 8192)  { int j = id2 >> 6, o = id2 & 63;  wt[24576 + id2] = w2a[o*128 + j]; return; }
  int id3 = id2 - 8192;
  if (id3 < 640)   { int j = id3 / 10, o = id3 % 10;  wt[32768 + id3] = w2b[o*64 + j]; return; }
  int id4 = id3 - 640;
  if (id4 < 4608) {
    int s = id4 >> 8, rem = id4 & 255, l = rem >> 2, r = rem & 3;
    int tap = s >> 1, h = s & 1;
    int oc = l & 15, j = l >> 4;
    int icl = 16*h + 4*j + r;
    float lo = c2w[oc*576 + icl*9 + tap];
    float hi = c2w[oc*576 + (icl+32)*9 + tap];
    ((unsigned*)wt)[33408 + id4] = packh2(lo, hi);
    return;
  }
  int id5 = id4 - 4608;
  if (id5 < 1024) {
    int nt = id5 >> 8, rem = id5 & 255, l = rem >> 2, r = rem & 3;
    int oc = nt*16 + (l & 15), j = l >> 4;
    int k0 = 8*j + 2*r;
    float lo = (k0     < 27) ? c1w[oc*27 + k0]     : 0.f;
    float hi = (k0 + 1 < 27) ? c1w[oc*27 + k0 + 1] : 0.f;
    ((unsigned*)wt)[38016 + id5] = packh2(lo, hi);
  }
}

// ---- K12 v5: r18 structure + VGPR trims to fit the 64-reg bucket (2 blocks/CU). ----
// Trims: (a) no valid[] — B1g weights are 0.0 for k>=27 so finite*0=0 exact;
// (b) conv1 bias added at pooling epilogue (frees bz1 during MFMA phase);
// (c) Bf2 1-deep in-loop prefetch (<=8 regs vs 72). launch_bounds(512,4) -> cap 64.
__global__ __launch_bounds__(512, 4) void k_conv12(
    const float* __restrict__ x,
    const uint4* __restrict__ B1g, const float* __restrict__ b1,
    const uint4* __restrict__ B2g, const float* __restrict__ b2,
    float* __restrict__ h2) {
  __shared__ float xs[3480];           // [3][34][34] f32, stride 1156
  __shared__ unsigned hsp[11664];      // [18][18][36] u32
  int b = blockIdx.x, t = threadIdx.x;
  int l = t & 63, w = t >> 6;          // 8 waves
  int m = l & 15, j = l >> 4;
  uint4 Bf1[4];
#pragma unroll
  for (int nt = 0; nt < 4; ++nt) Bf1[nt] = B1g[nt*64 + l];
  int offs[8];
#pragma unroll
  for (int q = 0; q < 8; ++q) {
    int kk = 8*j + q;
    int kc = (kk < 27) ? kk : 0;       // k>=27: B weight is 0.0 -> any finite A ok
    int c = kc / 9, rem = kc - 9*c, wr = rem / 3, cc = rem - 3*wr;
    offs[q] = c*1156 + wr*34 + cc;
  }
  for (int i = t; i < 3480; i += 512) xs[i] = 0.f;
  {
    uint4 z = make_uint4(0u,0u,0u,0u);
    uint4* hz = (uint4*)hsp;
    for (int i = t; i < 2916; i += 512) hz[i] = z;
  }
  __syncthreads();
  for (int i = t; i < 3072; i += 512) {
    int c = i >> 10, rem = i & 1023, gy = rem >> 5, gx = rem & 31;
    xs[c*1156 + (gy+1)*34 + gx + 1] = x[(size_t)b*3072 + i];
  }
  __syncthreads();
  // ---- conv1 (MFMA), bias-free accumulation ----
#pragma unroll
  for (int h = 0; h < 2; ++h) {
    f32x4v acc[2][2][4];
#pragma unroll
    for (int rr = 0; rr < 2; ++rr)
#pragma unroll
      for (int xh = 0; xh < 2; ++xh)
#pragma unroll
        for (int nt = 0; nt < 4; ++nt)
          acc[rr][xh][nt] = f32x4v{0.f, 0.f, 0.f, 0.f};
#pragma unroll
    for (int rr = 0; rr < 2; ++rr)
#pragma unroll
      for (int xh = 0; xh < 2; ++xh) {
        int base = (16*h + 2*w + rr)*34 + 16*xh + m;
        float v[8];
#pragma unroll
        for (int q = 0; q < 8; ++q) v[q] = xs[offs[q] + base];
        uint4 Au = make_uint4(packh2(v[0], v[1]), packh2(v[2], v[3]),
                              packh2(v[4], v[5]), packh2(v[6], v[7]));
        f16x8 Av = __builtin_bit_cast(f16x8, Au);
#pragma unroll
        for (int nt = 0; nt < 4; ++nt)
          acc[rr][xh][nt] = __builtin_amdgcn_mfma_f32_16x16x32_f16(
              Av, __builtin_bit_cast(f16x8, Bf1[nt]), acc[rr][xh][nt], 0, 0, 0);
      }
    // pool 2x2 + bias + relu + pack -> hsp (max commutes with +bias: RN monotone)
    {
      int pyg = 8*h + w;
#pragma unroll
      for (int ntp = 0; ntp < 2; ++ntp) {
        float bza = b1[ntp*16 + m];
        float bzb = b1[(ntp+2)*16 + m];
#pragma unroll
        for (int xh = 0; xh < 2; ++xh)
#pragma unroll
          for (int pv = 0; pv < 2; ++pv) {
            f32x4v aL0 = acc[0][xh][ntp],   aL1 = acc[1][xh][ntp];
            f32x4v aH0 = acc[0][xh][ntp+2], aH1 = acc[1][xh][ntp+2];
            float mlo = fmaxf(fmaxf(aL0[2*pv], aL0[2*pv+1]), fmaxf(aL1[2*pv], aL1[2*pv+1]));
            float mhi = fmaxf(fmaxf(aH0[2*pv], aH0[2*pv+1]), fmaxf(aH1[2*pv], aH1[2*pv+1]));
            int px = 8*xh + 2*j + pv;
            hsp[((pyg+1)*18 + px + 1)*36 + ntp*16 + m] =
                packh2(fmaxf(mlo + bza, 0.f), fmaxf(mhi + bzb, 0.f));
          }
      }
    }
  }
  __syncthreads();
  // ---- conv2 (MFMA), Bf2 in-loop prefetch ----
  float bz2 = b2[m];
  f32x4v a2[2];
  a2[0] = f32x4v{bz2, bz2, bz2, bz2};
  a2[1] = f32x4v{bz2, bz2, bz2, bz2};
  uint4 bnx = B2g[l];
#pragma unroll
  for (int s = 0; s < 18; ++s) {
    f16x8 Bv = __builtin_bit_cast(f16x8, bnx);
    if (s < 17) bnx = B2g[(s+1)*64 + l];
    const int tap = s >> 1, hh = s & 1;
    const int dy = tap / 3, dx = tap % 3;
#pragma unroll
    for (int tt = 0; tt < 2; ++tt) {
      int y = 2*w + tt;
      f16x8 Av = __builtin_bit_cast(f16x8,
          *(const uint4*)(hsp + ((y+dy)*18 + m + dx)*36 + 16*hh + 4*j));
      a2[tt] = __builtin_amdgcn_mfma_f32_16x16x32_f16(Av, Bv, a2[tt], 0, 0, 0);
    }
  }
  float* outb = h2 + (size_t)b*1024 + m*64;
#pragma unroll
  for (int vp = 0; vp < 2; ++vp) {
    float mm = fmaxf(fmaxf(a2[0][2*vp], a2[0][2*vp+1]),
                     fmaxf(a2[1][2*vp], a2[1][2*vp+1]));
    outb[w*8 + 2*j + vp] = fmaxf(mm, 0.f);
  }
}

// ---- Ktail v2 (r18 exact): one image per block, phase-parallel. ----
__global__ __launch_bounds__(256) void k_tail(const float* __restrict__ h2, const float* __restrict__ w,
                                              const float* __restrict__ bias, const float* __restrict__ Ag,
                                              const float* __restrict__ wt,
                                              const float* __restrict__ b1a, const float* __restrict__ b1b,
                                              const float* __restrict__ b2a, const float* __restrict__ b2b,
                                              float* __restrict__ out) {
  __shared__ float h3s[1600];
  __shared__ float As[1024];
  __shared__ float c3s[4][64];
  __shared__ float qs[256];
  __shared__ float red[256];
  __shared__ float h1s[64];
  __shared__ float hbv[128];
  __shared__ float h3v[64];
  int b = blockIdx.x, t = threadIdx.x;
#pragma unroll
  for (int k = 0; k < 4; ++k) As[k*256 + t] = Ag[k*256 + t];
  for (int i = t; i < 1600; i += 256) h3s[i] = 0.f;
  __syncthreads();
  {
    const float4* src = (const float4*)(h2 + (size_t)b*1024);
    float4 v = src[t];
    int e = 4*t;
    int ic = e >> 6, iy = (e >> 3) & 7, ix = e & 7;
    float* d = &h3s[ic*100 + (iy+1)*10 + ix + 1];
    d[0]=v.x; d[1]=v.y; d[2]=v.z; d[3]=v.w;
  }
  __syncthreads();
  {
    int oc = t >> 6, pos = t & 63;
    int y = pos >> 3, xo = pos & 7;
    float acc = bias[oc];
    const float* wp = w + oc*144;
    for (int ic = 0; ic < 16; ++ic) {
#pragma unroll
      for (int ky = 0; ky < 3; ++ky)
#pragma unroll
        for (int kx = 0; kx < 3; ++kx)
          acc = fmaf(wp[ic*9 + ky*3 + kx], h3s[ic*100 + (y+ky)*10 + (xo+kx)], acc);
    }
    c3s[oc][pos] = acc;
  }
  __syncthreads();
  {
    int p = t & 63, w4 = t >> 6;
    float v0[2], v1[2], v2[2], v3[2];
#pragma unroll
    for (int o = 0; o < 4; ++o) {
      float v = c3s[o][p];
      float lv = v > 0.f ? v : 0.01f*v;
      float sg = 1.f/(1.f + expf(-lv));
      float sv, cv;
      __sincosf(sg * (0.5f*PI_F), &sv, &cv);
      float* dst = (o==0)?v0:(o==1)?v1:(o==2)?v2:v3;
      dst[0] = cv; dst[1] = sv;
    }
    float pv[16];
#pragma unroll
    for (int i = 0; i < 16; ++i)
      pv[i] = v0[(i>>3)&1] * v1[(i>>2)&1] * v2[(i>>1)&1] * v3[i&1];
    const float4* Aw = (const float4*)(As + w4*256);
    float a = 0.f;
#pragma unroll
    for (int i = 0; i < 16; ++i) {
      float d = 0.f;
#pragma unroll
      for (int j4 = 0; j4 < 4; ++j4) {
        float4 av = Aw[i*4 + j4];
        d = fmaf(av.x, pv[j4*4+0], d);
        d = fmaf(av.y, pv[j4*4+1], d);
        d = fmaf(av.z, pv[j4*4+2], d);
        d = fmaf(av.w, pv[j4*4+3], d);
      }
      a = fmaf(pv[i], d, a);
    }
    qs[p*4 + w4] = a;
  }
  __syncthreads();
  const float* WT1a = wt;
  const float* WT1b = wt + 16384;
  const float* WT2a = wt + 24576;
  const float* WT2b = wt + 32768;
  {
    int o = t & 63, seg = t >> 6;
    float acc = 0.f;
    const float* wp = WT1a + seg*64*64 + o;
    const float* qp = qs + seg*64;
    for (int jj = 0; jj < 64; ++jj) acc = fmaf(wp[jj*64], qp[jj], acc);
    red[seg*64 + o] = acc;
  }
  __syncthreads();
  if (t < 64) {
    float s = red[t] + red[64+t] + red[128+t] + red[192+t] + b1a[t];
    h1s[t] = fmaxf(s, 0.f);
  }
  __syncthreads();
  if (t < 128) {
    float acc = b1b[t];
    for (int jj = 0; jj < 64; ++jj) acc = fmaf(WT1b[jj*128 + t], h1s[jj], acc);
    hbv[t] = acc;
  }
  __syncthreads();
  {
    int o = t & 63, seg = t >> 6;
    float acc = 0.f;
    const float* wp = WT2a + seg*32*64 + o;
    const float* hp = hbv + seg*32;
    for (int jj = 0; jj < 32; ++jj) acc = fmaf(wp[jj*64], hp[jj], acc);
    red[seg*64 + o] = acc;
  }
  __syncthreads();
  if (t < 64) {
    float s = red[t] + red[64+t] + red[128+t] + red[192+t] + b2a[t];
    h3v[t] = fmaxf(s, 0.f);
  }
  __syncthreads();
  if (t < 10) {
    float o = b2b[t];
    for (int jj = 0; jj < 64; ++jj) o = fmaf(WT2b[jj*10 + t], h3v[jj], o);
    out[(size_t)b*10 + t] = o;
  }
}

extern "C" void kernel_launch(void* const* d_in, const int* in_sizes, int n_in,
                              void* d_out, int out_size, void* d_ws, size_t ws_size,
                              hipStream_t stream) {
  const float* x       = (const float*)d_in[0];
  const float* conv1_w = (const float*)d_in[1];
  const float* conv1_b = (const float*)d_in[2];
  const float* conv2_w = (const float*)d_in[3];
  const float* conv2_b = (const float*)d_in[4];
  const float* conv3_w = (const float*)d_in[5];
  const float* conv3_b = (const float*)d_in[6];
  const float* qw_u3   = (const float*)d_in[7];
  const float* qw_ang  = (const float*)d_in[8];
  const float* fc1a_w  = (const float*)d_in[9];
  const float* fc1a_b  = (const float*)d_in[10];
  const float* fc1b_w  = (const float*)d_in[11];
  const float* fc1b_b  = (const float*)d_in[12];
  const float* fc2a_w  = (const float*)d_in[13];
  const float* fc2a_b  = (const float*)d_in[14];
  const float* fc2b_w  = (const float*)d_in[15];
  const float* fc2b_b  = (const float*)d_in[16];
  float* out = (float*)d_out;

  float* ws  = (float*)d_ws;
  float* A   = ws;                      // 1024 floats
  float* WT  = ws + 1024;               // fc transposes (33408) + conv2 B (4608 u32) + conv1 B (1024 u32)
  const uint4* BG  = (const uint4*)((const unsigned*)WT + 33408);
  const uint4* B1G = (const uint4*)((const unsigned*)WT + 38016);
  float* h2  = ws + 17083008;           // 1048576 floats (1024x16x8x8)

  k_setup <<<168,  256, 0, stream>>>(fc1a_w, fc1b_w, fc2a_w, fc2b_w, conv2_w, conv1_w, conv1_b,
                                     qw_u3, qw_ang, WT, A);
  k_conv12<<<1024, 512, 0, stream>>>(x, B1G, conv1_b, BG, conv2_b, h2);
  k_tail  <<<1024, 256, 0, stream>>>(h2, conv3_w, conv3_b, A, WT,
                                     fc1a_b, fc1b_b, fc2a_b, fc2b_b, out);
}

// Round 22
// 45.858 us; speedup vs baseline: 2.0265x; 1.0120x over previous
//
#include <hip/hip_runtime.h>
#include <math.h>

#define PI_F 3.14159265358979323846f

typedef _Float16 half2_t __attribute__((ext_vector_type(2)));
typedef _Float16 f16x8 __attribute__((ext_vector_type(8)));
typedef float f32x4v __attribute__((ext_vector_type(4)));

__device__ __forceinline__ unsigned packh2(float lo, float hi) {
  unsigned short l = __builtin_bit_cast(unsigned short, (_Float16)lo);
  unsigned short h = __builtin_bit_cast(unsigned short, (_Float16)hi);
  return (unsigned)l | ((unsigned)h << 16);
}

__device__ __forceinline__ unsigned pk16(_Float16 a, _Float16 b) {
  unsigned short ua = __builtin_bit_cast(unsigned short, a);
  unsigned short ub = __builtin_bit_cast(unsigned short, b);
  return (unsigned)ua | ((unsigned)ub << 16);
}

struct c2 { float x, y; };
__device__ __forceinline__ c2 cmul(c2 a, c2 b){ return c2{a.x*b.x - a.y*b.y, a.x*b.y + a.y*b.x}; }
__device__ __forceinline__ c2 cadd(c2 a, c2 b){ return c2{a.x+b.x, a.y+b.y}; }

__device__ __forceinline__ void rot2(c2 &a, c2 &b, c2 g00, c2 g01, c2 g10, c2 g11) {
  c2 na = cadd(cmul(g00,a), cmul(g01,b));
  c2 nb = cadd(cmul(g10,a), cmul(g11,b));
  a = na; b = nb;
}

__device__ __forceinline__ void mk_u3(float th, float ph, float la,
                                      c2 &g00, c2 &g01, c2 &g10, c2 &g11) {
  float ch = cosf(0.5f*th), sh = sinf(0.5f*th);
  float cl = cosf(la), sl = sinf(la);
  float cp = cosf(ph), sp = sinf(ph);
  float cpl = cp*cl - sp*sl, spl = sp*cl + cp*sl;
  g00 = c2{ch, 0.f};
  g01 = c2{-cl*sh, -sl*sh};
  g10 = c2{cp*sh, sp*sh};
  g11 = c2{cpl*ch, spl*ch};
}

template<int MA, int MB>
__device__ __forceinline__ void apply2q(c2 psi[16], const c2 M[16]) {
#pragma unroll
  for (int r = 0; r < 16; ++r) {
    if (r & (MA | MB)) continue;
    c2 a = psi[r], b = psi[r|MB], c = psi[r|MA], d = psi[r|MA|MB];
    psi[r]        = cadd(cadd(cmul(M[0],a),  cmul(M[1],b)),  cadd(cmul(M[2],c),  cmul(M[3],d)));
    psi[r|MB]     = cadd(cadd(cmul(M[4],a),  cmul(M[5],b)),  cadd(cmul(M[6],c),  cmul(M[7],d)));
    psi[r|MA]     = cadd(cadd(cmul(M[8],a),  cmul(M[9],b)),  cadd(cmul(M[10],c), cmul(M[11],d)));
    psi[r|MA|MB]  = cadd(cadd(cmul(M[12],a), cmul(M[13],b)), cadd(cmul(M[14],c), cmul(M[15],d)));
  }
}

// ------- Ksetup: blocks 0..166 = weight transposes/packs; block 167 = qmat. -------
__global__ __launch_bounds__(256) void k_setup(const float* __restrict__ w1a, const float* __restrict__ w1b,
                                               const float* __restrict__ w2a, const float* __restrict__ w2b,
                                               const float* __restrict__ c2w,
                                               const float* __restrict__ c1w, const float* __restrict__ c1b,
                                               const float* __restrict__ qw_u3,
                                               const float* __restrict__ qw_ang,
                                               float* __restrict__ wt, float* __restrict__ A) {
  __shared__ c2 SU[2][16];
  __shared__ float Ur[16*17], Ui[16*17];
  int t = threadIdx.x;
  if (blockIdx.x == 167) {
    if (t < 8) {
      int L = t >> 2, col = t & 3;
      c2 s[4];
#pragma unroll
      for (int i = 0; i < 4; ++i) s[i] = c2{(i==col)?1.f:0.f, 0.f};
      const float* u = qw_u3 + 12*L;
      const float* g = qw_ang + 3*L;
      c2 g00,g01,g10,g11;
      mk_u3(u[0],u[1],u[2], g00,g01,g10,g11);
      rot2(s[0],s[2], g00,g01,g10,g11); rot2(s[1],s[3], g00,g01,g10,g11);
      mk_u3(u[3],u[4],u[5], g00,g01,g10,g11);
      rot2(s[0],s[1], g00,g01,g10,g11); rot2(s[2],s[3], g00,g01,g10,g11);
      { c2 tmp = s[2]; s[2] = s[3]; s[3] = tmp; }
      { float c = cosf(0.5f*g[0]), sn = sinf(0.5f*g[0]);
        c2 r00{c,0.f}, r01{-sn,0.f}, r10{sn,0.f}, r11{c,0.f};
        rot2(s[0],s[2], r00,r01,r10,r11); rot2(s[1],s[3], r00,r01,r10,r11); }
      { float c = cosf(0.5f*g[1]), sn = sinf(0.5f*g[1]);
        c2 e0{c,-sn}, e1{c,sn};
        s[0]=cmul(s[0],e0); s[1]=cmul(s[1],e1); s[2]=cmul(s[2],e0); s[3]=cmul(s[3],e1); }
      { c2 tmp = s[1]; s[1] = s[3]; s[3] = tmp; }
      { float c = cosf(0.5f*g[2]), sn = sinf(0.5f*g[2]);
        c2 r00{c,0.f}, r01{-sn,0.f}, r10{sn,0.f}, r11{c,0.f};
        rot2(s[0],s[2], r00,r01,r10,r11); rot2(s[1],s[3], r00,r01,r10,r11); }
      { c2 tmp = s[2]; s[2] = s[3]; s[3] = tmp; }
      mk_u3(u[6],u[7],u[8], g00,g01,g10,g11);
      rot2(s[0],s[2], g00,g01,g10,g11); rot2(s[1],s[3], g00,g01,g10,g11);
      mk_u3(u[9],u[10],u[11], g00,g01,g10,g11);
      rot2(s[0],s[1], g00,g01,g10,g11); rot2(s[2],s[3], g00,g01,g10,g11);
#pragma unroll
      for (int k = 0; k < 4; ++k) SU[L][k*4 + col] = s[k];
    }
    __syncthreads();
    if (t < 16) {
      c2 psi[16];
#pragma unroll
      for (int i = 0; i < 16; ++i) psi[i] = c2{(i==t)?1.f:0.f, 0.f};
#pragma unroll
      for (int l = 0; l < 2; ++l) {
        c2 M[16];
#pragma unroll
        for (int k = 0; k < 16; ++k) M[k] = SU[l][k];
        apply2q<8,4>(psi, M);
        apply2q<4,2>(psi, M);
        apply2q<2,1>(psi, M);
        apply2q<1,8>(psi, M);
      }
#pragma unroll
      for (int k = 0; k < 16; ++k) { Ur[k*17+t] = psi[k].x; Ui[k*17+t] = psi[k].y; }
    }
    __syncthreads();
    {
      int i = t >> 4, j = t & 15;
      float a0=0.f,a1=0.f,a2=0.f,a3=0.f;
#pragma unroll
      for (int k = 0; k < 16; ++k) {
        float pr = Ur[k*17+i]*Ur[k*17+j] + Ui[k*17+i]*Ui[k*17+j];
        a0 += ((k>>3)&1) ? -pr : pr;
        a1 += ((k>>2)&1) ? -pr : pr;
        a2 += ((k>>1)&1) ? -pr : pr;
        a3 += ( k     &1) ? -pr : pr;
      }
      A[0*256 + t] = a0; A[1*256 + t] = a1; A[2*256 + t] = a2; A[3*256 + t] = a3;
    }
    return;
  }
  int id = blockIdx.x*256 + t;
  if (id < 16384) { int j = id >> 6, o = id & 63;  wt[id] = w1a[o*256 + j]; return; }
  int id1 = id - 16384;
  if (id1 < 8192)  { int j = id1 >> 7, o = id1 & 127; wt[16384 + id1] = w1b[o*64 + j]; return; }
  int id2 = id1 - 8192;
  if (id2 < 8192)  { int j = id2 >> 6, o = id2 & 63;  wt[24576 + id2] = w2a[o*128 + j]; return; }
  int id3 = id2 - 8192;
  if (id3 < 640)   { int j = id3 / 10, o = id3 % 10;  wt[32768 + id3] = w2b[o*64 + j]; return; }
  int id4 = id3 - 640;
  if (id4 < 4608) {
    int s = id4 >> 8, rem = id4 & 255, l = rem >> 2, r = rem & 3;
    int tap = s >> 1, h = s & 1;
    int oc = l & 15, j = l >> 4;
    int icl = 16*h + 4*j + r;
    float lo = c2w[oc*576 + icl*9 + tap];
    float hi = c2w[oc*576 + (icl+32)*9 + tap];
    ((unsigned*)wt)[33408 + id4] = packh2(lo, hi);
    return;
  }
  int id5 = id4 - 4608;
  if (id5 < 1024) {
    int nt = id5 >> 8, rem = id5 & 255, l = rem >> 2, r = rem & 3;
    int oc = nt*16 + (l & 15), j = l >> 4;
    int k0 = 8*j + 2*r;
    float lo = (k0     < 27) ? c1w[oc*27 + k0]     : 0.f;
    float hi = (k0 + 1 < 27) ? c1w[oc*27 + k0 + 1] : 0.f;
    ((unsigned*)wt)[38016 + id5] = packh2(lo, hi);
  }
}

// ---- K12 v6: r21 (VGPR-trimmed) + f16 xs. RNE at staging == RNE at pack =>
// bit-identical. LDS 53.6 KB -> 3 blocks/CU if VGPR <= 85 (24 waves/CU).
__global__ __launch_bounds__(512, 4) void k_conv12(
    const float* __restrict__ x,
    const uint4* __restrict__ B1g, const float* __restrict__ b1,
    const uint4* __restrict__ B2g, const float* __restrict__ b2,
    float* __restrict__ h2) {
  __shared__ _Float16 xs[3468];        // [3][34][34] f16, strides 1156/34
  __shared__ unsigned hsp[11664];      // [18][18][36] u32
  int b = blockIdx.x, t = threadIdx.x;
  int l = t & 63, w = t >> 6;          // 8 waves
  int m = l & 15, j = l >> 4;
  uint4 Bf1[4];
#pragma unroll
  for (int nt = 0; nt < 4; ++nt) Bf1[nt] = B1g[nt*64 + l];
  int offs[8];
#pragma unroll
  for (int q = 0; q < 8; ++q) {
    int kk = 8*j + q;
    int kc = (kk < 27) ? kk : 0;       // k>=27: B weight is 0.0 -> any finite A ok
    int c = kc / 9, rem = kc - 9*c, wr = rem / 3, cc = rem - 3*wr;
    offs[q] = c*1156 + wr*34 + cc;
  }
  {
    unsigned* xz = (unsigned*)xs;      // 1734 u32
    for (int i = t; i < 1734; i += 512) xz[i] = 0u;
    uint4 z = make_uint4(0u,0u,0u,0u);
    uint4* hz = (uint4*)hsp;
    for (int i = t; i < 2916; i += 512) hz[i] = z;
  }
  __syncthreads();
  for (int i = t; i < 3072; i += 512) {
    int c = i >> 10, rem = i & 1023, gy = rem >> 5, gx = rem & 31;
    xs[c*1156 + (gy+1)*34 + gx + 1] = (_Float16)x[(size_t)b*3072 + i];
  }
  __syncthreads();
  // ---- conv1 (MFMA), bias-free accumulation ----
#pragma unroll
  for (int h = 0; h < 2; ++h) {
    f32x4v acc[2][2][4];
#pragma unroll
    for (int rr = 0; rr < 2; ++rr)
#pragma unroll
      for (int xh = 0; xh < 2; ++xh)
#pragma unroll
        for (int nt = 0; nt < 4; ++nt)
          acc[rr][xh][nt] = f32x4v{0.f, 0.f, 0.f, 0.f};
#pragma unroll
    for (int rr = 0; rr < 2; ++rr)
#pragma unroll
      for (int xh = 0; xh < 2; ++xh) {
        int base = (16*h + 2*w + rr)*34 + 16*xh + m;
        _Float16 v[8];
#pragma unroll
        for (int q = 0; q < 8; ++q) v[q] = xs[offs[q] + base];
        uint4 Au = make_uint4(pk16(v[0], v[1]), pk16(v[2], v[3]),
                              pk16(v[4], v[5]), pk16(v[6], v[7]));
        f16x8 Av = __builtin_bit_cast(f16x8, Au);
#pragma unroll
        for (int nt = 0; nt < 4; ++nt)
          acc[rr][xh][nt] = __builtin_amdgcn_mfma_f32_16x16x32_f16(
              Av, __builtin_bit_cast(f16x8, Bf1[nt]), acc[rr][xh][nt], 0, 0, 0);
      }
    // pool 2x2 + bias + relu + pack -> hsp (max commutes with +bias: RN monotone)
    {
      int pyg = 8*h + w;
#pragma unroll
      for (int ntp = 0; ntp < 2; ++ntp) {
        float bza = b1[ntp*16 + m];
        float bzb = b1[(ntp+2)*16 + m];
#pragma unroll
        for (int xh = 0; xh < 2; ++xh)
#pragma unroll
          for (int pv = 0; pv < 2; ++pv) {
            f32x4v aL0 = acc[0][xh][ntp],   aL1 = acc[1][xh][ntp];
            f32x4v aH0 = acc[0][xh][ntp+2], aH1 = acc[1][xh][ntp+2];
            float mlo = fmaxf(fmaxf(aL0[2*pv], aL0[2*pv+1]), fmaxf(aL1[2*pv], aL1[2*pv+1]));
            float mhi = fmaxf(fmaxf(aH0[2*pv], aH0[2*pv+1]), fmaxf(aH1[2*pv], aH1[2*pv+1]));
            int px = 8*xh + 2*j + pv;
            hsp[((pyg+1)*18 + px + 1)*36 + ntp*16 + m] =
                packh2(fmaxf(mlo + bza, 0.f), fmaxf(mhi + bzb, 0.f));
          }
      }
    }
  }
  __syncthreads();
  // ---- conv2 (MFMA), Bf2 in-loop prefetch ----
  float bz2 = b2[m];
  f32x4v a2[2];
  a2[0] = f32x4v{bz2, bz2, bz2, bz2};
  a2[1] = f32x4v{bz2, bz2, bz2, bz2};
  uint4 bnx = B2g[l];
#pragma unroll
  for (int s = 0; s < 18; ++s) {
    f16x8 Bv = __builtin_bit_cast(f16x8, bnx);
    if (s < 17) bnx = B2g[(s+1)*64 + l];
    const int tap = s >> 1, hh = s & 1;
    const int dy = tap / 3, dx = tap % 3;
#pragma unroll
    for (int tt = 0; tt < 2; ++tt) {
      int y = 2*w + tt;
      f16x8 Av = __builtin_bit_cast(f16x8,
          *(const uint4*)(hsp + ((y+dy)*18 + m + dx)*36 + 16*hh + 4*j));
      a2[tt] = __builtin_amdgcn_mfma_f32_16x16x32_f16(Av, Bv, a2[tt], 0, 0, 0);
    }
  }
  float* outb = h2 + (size_t)b*1024 + m*64;
#pragma unroll
  for (int vp = 0; vp < 2; ++vp) {
    float mm = fmaxf(fmaxf(a2[0][2*vp], a2[0][2*vp+1]),
                     fmaxf(a2[1][2*vp], a2[1][2*vp+1]));
    outb[w*8 + 2*j + vp] = fmaxf(mm, 0.f);
  }
}

// ---- Ktail v2 (r18 exact): one image per block, phase-parallel. ----
__global__ __launch_bounds__(256) void k_tail(const float* __restrict__ h2, const float* __restrict__ w,
                                              const float* __restrict__ bias, const float* __restrict__ Ag,
                                              const float* __restrict__ wt,
                                              const float* __restrict__ b1a, const float* __restrict__ b1b,
                                              const float* __restrict__ b2a, const float* __restrict__ b2b,
                                              float* __restrict__ out) {
  __shared__ float h3s[1600];
  __shared__ float As[1024];
  __shared__ float c3s[4][64];
  __shared__ float qs[256];
  __shared__ float red[256];
  __shared__ float h1s[64];
  __shared__ float hbv[128];
  __shared__ float h3v[64];
  int b = blockIdx.x, t = threadIdx.x;
#pragma unroll
  for (int k = 0; k < 4; ++k) As[k*256 + t] = Ag[k*256 + t];
  for (int i = t; i < 1600; i += 256) h3s[i] = 0.f;
  __syncthreads();
  {
    const float4* src = (const float4*)(h2 + (size_t)b*1024);
    float4 v = src[t];
    int e = 4*t;
    int ic = e >> 6, iy = (e >> 3) & 7, ix = e & 7;
    float* d = &h3s[ic*100 + (iy+1)*10 + ix + 1];
    d[0]=v.x; d[1]=v.y; d[2]=v.z; d[3]=v.w;
  }
  __syncthreads();
  {
    int oc = t >> 6, pos = t & 63;
    int y = pos >> 3, xo = pos & 7;
    float acc = bias[oc];
    const float* wp = w + oc*144;
    for (int ic = 0; ic < 16; ++ic) {
#pragma unroll
      for (int ky = 0; ky < 3; ++ky)
#pragma unroll
        for (int kx = 0; kx < 3; ++kx)
          acc = fmaf(wp[ic*9 + ky*3 + kx], h3s[ic*100 + (y+ky)*10 + (xo+kx)], acc);
    }
    c3s[oc][pos] = acc;
  }
  __syncthreads();
  {
    int p = t & 63, w4 = t >> 6;
    float v0[2], v1[2], v2[2], v3[2];
#pragma unroll
    for (int o = 0; o < 4; ++o) {
      float v = c3s[o][p];
      float lv = v > 0.f ? v : 0.01f*v;
      float sg = 1.f/(1.f + expf(-lv));
      float sv, cv;
      __sincosf(sg * (0.5f*PI_F), &sv, &cv);
      float* dst = (o==0)?v0:(o==1)?v1:(o==2)?v2:v3;
      dst[0] = cv; dst[1] = sv;
    }
    float pv[16];
#pragma unroll
    for (int i = 0; i < 16; ++i)
      pv[i] = v0[(i>>3)&1] * v1[(i>>2)&1] * v2[(i>>1)&1] * v3[i&1];
    const float4* Aw = (const float4*)(As + w4*256);
    float a = 0.f;
#pragma unroll
    for (int i = 0; i < 16; ++i) {
      float d = 0.f;
#pragma unroll
      for (int j4 = 0; j4 < 4; ++j4) {
        float4 av = Aw[i*4 + j4];
        d = fmaf(av.x, pv[j4*4+0], d);
        d = fmaf(av.y, pv[j4*4+1], d);
        d = fmaf(av.z, pv[j4*4+2], d);
        d = fmaf(av.w, pv[j4*4+3], d);
      }
      a = fmaf(pv[i], d, a);
    }
    qs[p*4 + w4] = a;
  }
  __syncthreads();
  const float* WT1a = wt;
  const float* WT1b = wt + 16384;
  const float* WT2a = wt + 24576;
  const float* WT2b = wt + 32768;
  {
    int o = t & 63, seg = t >> 6;
    float acc = 0.f;
    const float* wp = WT1a + seg*64*64 + o;
    const float* qp = qs + seg*64;
    for (int jj = 0; jj < 64; ++jj) acc = fmaf(wp[jj*64], qp[jj], acc);
    red[seg*64 + o] = acc;
  }
  __syncthreads();
  if (t < 64) {
    float s = red[t] + red[64+t] + red[128+t] + red[192+t] + b1a[t];
    h1s[t] = fmaxf(s, 0.f);
  }
  __syncthreads();
  if (t < 128) {
    float acc = b1b[t];
    for (int jj = 0; jj < 64; ++jj) acc = fmaf(WT1b[jj*128 + t], h1s[jj], acc);
    hbv[t] = acc;
  }
  __syncthreads();
  {
    int o = t & 63, seg = t >> 6;
    float acc = 0.f;
    const float* wp = WT2a + seg*32*64 + o;
    const float* hp = hbv + seg*32;
    for (int jj = 0; jj < 32; ++jj) acc = fmaf(wp[jj*64], hp[jj], acc);
    red[seg*64 + o] = acc;
  }
  __syncthreads();
  if (t < 64) {
    float s = red[t] + red[64+t] + red[128+t] + red[192+t] + b2a[t];
    h3v[t] = fmaxf(s, 0.f);
  }
  __syncthreads();
  if (t < 10) {
    float o = b2b[t];
    for (int jj = 0; jj < 64; ++jj) o = fmaf(WT2b[jj*10 + t], h3v[jj], o);
    out[(size_t)b*10 + t] = o;
  }
}

extern "C" void kernel_launch(void* const* d_in, const int* in_sizes, int n_in,
                              void* d_out, int out_size, void* d_ws, size_t ws_size,
                              hipStream_t stream) {
  const float* x       = (const float*)d_in[0];
  const float* conv1_w = (const float*)d_in[1];
  const float* conv1_b = (const float*)d_in[2];
  const float* conv2_w = (const float*)d_in[3];
  const float* conv2_b = (const float*)d_in[4];
  const float* conv3_w = (const float*)d_in[5];
  const float* conv3_b = (const float*)d_in[6];
  const float* qw_u3   = (const float*)d_in[7];
  const float* qw_ang  = (const float*)d_in[8];
  const float* fc1a_w  = (const float*)d_in[9];
  const float* fc1a_b  = (const float*)d_in[10];
  const float* fc1b_w  = (const float*)d_in[11];
  const float* fc1b_b  = (const float*)d_in[12];
  const float* fc2a_w  = (const float*)d_in[13];
  const float* fc2a_b  = (const float*)d_in[14];
  const float* fc2b_w  = (const float*)d_in[15];
  const float* fc2b_b  = (const float*)d_in[16];
  float* out = (float*)d_out;

  float* ws  = (float*)d_ws;
  float* A   = ws;                      // 1024 floats
  float* WT  = ws + 1024;               // fc transposes (33408) + conv2 B (4608 u32) + conv1 B (1024 u32)
  const uint4* BG  = (const uint4*)((const unsigned*)WT + 33408);
  const uint4* B1G = (const uint4*)((const unsigned*)WT + 38016);
  float* h2  = ws + 17083008;           // 1048576 floats (1024x16x8x8)

  k_setup <<<168,  256, 0, stream>>>(fc1a_w, fc1b_w, fc2a_w, fc2b_w, conv2_w, conv1_w, conv1_b,
                                     qw_u3, qw_ang, WT, A);
  k_conv12<<<1024, 512, 0, stream>>>(x, B1G, conv1_b, BG, conv2_b, h2);
  k_tail  <<<1024, 256, 0, stream>>>(h2, conv3_w, conv3_b, A, WT,
                                     fc1a_b, fc1b_b, fc2a_b, fc2b_b, out);
}